// Round 19
// baseline (1904.086 us; speedup 1.0000x reference)
//
#include <hip/hip_runtime.h>
#include <hip/hip_bf16.h>

#define HD 1024
#define BB 512
#define SS 64
#define N3 3072
#define NC 9216      // Cbuf cols (bf16): gi2 | gh1 | gh2
#define ND 9
#define VC 4
#define KI 832       // padded K for init GEMM (784 -> 13*64)

typedef __attribute__((ext_vector_type(8))) short bf16x8;
typedef __attribute__((ext_vector_type(4))) float f32x4;

__device__ __forceinline__ ushort f2b(float f) {
    unsigned u = __builtin_bit_cast(unsigned, f);
    u += 0x7fffu + ((u >> 16) & 1u);          // round-to-nearest-even
    return (ushort)(u >> 16);
}

__device__ __forceinline__ float b2f(ushort u) {
    unsigned x = ((unsigned)u) << 16;
    return __builtin_bit_cast(float, x);
}

__device__ __forceinline__ float sigf(float x) {
    return 1.f / (1.f + __expf(-x));
}

__device__ __forceinline__ void gld_lds16(const void* g, void* l) {
    __builtin_amdgcn_global_load_lds(
        (const __attribute__((address_space(1))) unsigned int*)g,
        (__attribute__((address_space(3))) unsigned int*)l, 16, 0, 0);
}

// ============================================================================
// prep kernels (round-16 exact)
// ============================================================================
__global__ __launch_bounds__(256) void prep_w(
    const float* __restrict__ Wih2, const float* __restrict__ Whh1,
    const float* __restrict__ Whh2, ushort* __restrict__ Wcat)
{
    const int row = blockIdx.x;
    const float* src = row < 3072 ? Wih2 + (size_t)row * HD
                     : row < 6144 ? Whh1 + (size_t)(row - 3072) * HD
                                  : Whh2 + (size_t)(row - 6144) * HD;
    const int c = threadIdx.x * 4;
    float4 v = *(const float4*)(src + c);
    ushort4 o;
    o.x = f2b(v.x); o.y = f2b(v.y); o.z = f2b(v.z); o.w = f2b(v.w);
    *(ushort4*)(Wcat + (size_t)row * HD + c) = o;
}

__global__ __launch_bounds__(256) void prep_wt1(
    const float* __restrict__ Wih1, ushort* __restrict__ Wt1b)
{
    const int g = blockIdx.x * 256 + threadIdx.x;
    #pragma unroll
    for (int c = 0; c < 22; ++c)
        Wt1b[c * N3 + g] = f2b(Wih1[(size_t)g * 22 + c]);
}

__global__ __launch_bounds__(256) void prep_acat(
    const float* __restrict__ z, const float* __restrict__ ne,
    const float* __restrict__ gc, ushort* __restrict__ Acat)
{
    const int b = blockIdx.x;
    const int t = threadIdx.x;
    if (t >= 208) return;
    const int c = t * 4;
    float4 v = make_float4(0.f, 0.f, 0.f, 0.f);
    if (c < 256)      v = *(const float4*)(z  + (size_t)b * 256 + c);
    else if (c < 768) v = *(const float4*)(ne + (size_t)b * 512 + (c - 256));
    else if (c < 784) v = *(const float4*)(gc + (size_t)b * 16  + (c - 768));
    ushort4 o;
    o.x = f2b(v.x); o.y = f2b(v.y); o.z = f2b(v.z); o.w = f2b(v.w);
    *(ushort4*)(Acat + (size_t)b * KI + c) = o;
}

__global__ __launch_bounds__(256) void prep_win(
    const float* __restrict__ W_in, ushort* __restrict__ W_inb)
{
    const int r = blockIdx.x;
    const int t = threadIdx.x;
    if (t >= 208) return;
    const int c = t * 4;
    ushort4 o = {0, 0, 0, 0};
    if (c < 784) {
        float4 v = *(const float4*)(W_in + (size_t)r * 784 + c);
        o.x = f2b(v.x); o.y = f2b(v.y); o.z = f2b(v.z); o.w = f2b(v.w);
    }
    *(ushort4*)(W_inb + (size_t)r * KI + c) = o;
}

// ============================================================================
// k_init: h1 = tanh(Acat @ W_inb^T + b_in). BK=64 dbuf (verified R9-R18).
// ============================================================================
__global__ __launch_bounds__(256) void k_init(
    const ushort* __restrict__ Acat, const ushort* __restrict__ W_inb,
    const float* __restrict__ b_in, float* __restrict__ h1, ushort* __restrict__ h1b)
{
    __shared__ __align__(16) ushort As[2 * 4096];
    __shared__ __align__(16) ushort Bs[2 * 4096];
    const int t = blockIdx.x;
    const int nt = t >> 3, mt = t & 7;

    const int tid = threadIdx.x;
    const int w = tid >> 6, l = tid & 63;
    const int lr = l >> 3;
    const int sw = ((l & 7) ^ lr) << 3;

    const ushort* Ag0 = Acat + ((size_t)(mt << 6) + 16 * w + lr) * KI + sw;
    const ushort* Ag1 = Ag0 + 8 * KI;
    const ushort* Bg0 = W_inb + ((size_t)(nt << 6) + 16 * w + lr) * KI + sw;
    const ushort* Bg1 = Bg0 + 8 * KI;
    const int o0 = (16 * w) * 64, o1 = (16 * w + 8) * 64;

    gld_lds16(Ag0, As + o0); gld_lds16(Ag1, As + o1);
    gld_lds16(Bg0, Bs + o0); gld_lds16(Bg1, Bs + o1);

    const int wm = (w >> 1) << 5, wn = (w & 1) << 5;
    const int fr = l & 15, fc = l >> 4;
    const int ra0 = wm + fr, ra1 = wm + 16 + fr;
    const int rb0 = wn + fr, rb1 = wn + 16 + fr;

    f32x4 acc[2][2] = {};
    for (int kt = 0; kt < 13; ++kt) {
        const int cb = (kt & 1) << 12;
        __syncthreads();
        if (kt + 1 < 13) {
            const int nb = ((kt + 1) & 1) << 12;
            const int ko = (kt + 1) << 6;
            gld_lds16(Ag0 + ko, As + nb + o0);
            gld_lds16(Ag1 + ko, As + nb + o1);
            gld_lds16(Bg0 + ko, Bs + nb + o0);
            gld_lds16(Bg1 + ko, Bs + nb + o1);
        }
        #pragma unroll
        for (int kk = 0; kk < 2; ++kk) {
            const int c = (kk << 2) + fc;
            bf16x8 a0 = *(const bf16x8*)(As + cb + ra0 * 64 + ((c ^ (ra0 & 7)) << 3));
            bf16x8 a1 = *(const bf16x8*)(As + cb + ra1 * 64 + ((c ^ (ra1 & 7)) << 3));
            bf16x8 b0 = *(const bf16x8*)(Bs + cb + rb0 * 64 + ((c ^ (rb0 & 7)) << 3));
            bf16x8 b1 = *(const bf16x8*)(Bs + cb + rb1 * 64 + ((c ^ (rb1 & 7)) << 3));
            acc[0][0] = __builtin_amdgcn_mfma_f32_16x16x32_bf16(a0, b0, acc[0][0], 0, 0, 0);
            acc[0][1] = __builtin_amdgcn_mfma_f32_16x16x32_bf16(a0, b1, acc[0][1], 0, 0, 0);
            acc[1][0] = __builtin_amdgcn_mfma_f32_16x16x32_bf16(a1, b0, acc[1][0], 0, 0, 0);
            acc[1][1] = __builtin_amdgcn_mfma_f32_16x16x32_bf16(a1, b1, acc[1][1], 0, 0, 0);
        }
    }

    const int row0 = (mt << 6) + wm;
    const int col0 = (nt << 6) + wn + fr;
    const float b0v = b_in[col0], b1v = b_in[col0 + 16];
    #pragma unroll
    for (int i = 0; i < 2; ++i) {
        #pragma unroll
        for (int r = 0; r < 4; ++r) {
            const int row = row0 + i * 16 + fc * 4 + r;
            const float v0 = tanhf(acc[i][0][r] + b0v);
            const float v1 = tanhf(acc[i][1][r] + b1v);
            h1[(size_t)row * HD + col0]       = v0;
            h1b[(size_t)row * HD + col0]      = f2b(v0);
            h1[(size_t)row * HD + col0 + 16]  = v1;
            h1b[(size_t)row * HD + col0 + 16] = f2b(v1);
        }
    }
}

// ============================================================================
// gemm3: Cbuf(bf16)[512, 9216] = [h1b@Wih2^T | h1b@Whh1^T | h2b@Whh2^T]
// BK=128 single-buffered (32 KB LDS): 8 k-iters -> HALF the barrier drains
// of the BK=64 version, same total loads/MFMA, LDS-occupancy 5 blocks/CU
// >= grid's 4.5 resident (TLP preserved). XOR-16 swizzle: source chunk
// ch ^ (row&15) on staging, read at (kk*4+fc) ^ (ra&15) — same involution.
// ============================================================================
__global__ __launch_bounds__(256) void gemm3(
    const ushort* __restrict__ h1b, const ushort* __restrict__ h2b,
    const ushort* __restrict__ Wcat, ushort* __restrict__ Cbuf, int ntb, int skip48)
{
    __shared__ __align__(16) ushort As[64 * 128];   // [64][128] linear, 16KB
    __shared__ __align__(16) ushort Ws[64 * 128];

    const int flat = blockIdx.x + (blockIdx.y << 3);
    const int id   = (flat & 7) * gridDim.y + (flat >> 3);
    const int bm   = (id & 7) << 6;
    int nt         = (id >> 3) + ntb;          // global n-tile
    if (skip48 && nt >= 48) nt += 48;          // skip gh1 section

    const ushort* Amat = (nt < 96) ? h1b : h2b;
    const ushort* W    = Wcat + (size_t)(nt << 6) * HD;

    const int tid = threadIdx.x;
    const int w   = tid >> 6;
    const int l   = tid & 63;

    // staging: 4 loads per matrix per wave; load li covers rows 16w+4li..+3.
    // lane l: srow4 = l>>4 (0..3), ch = l&15; source chunk = ch ^ (4li+srow4).
    const int srow4 = l >> 4;
    const int ch    = l & 15;
    const int r0 = srow4, r1 = 4 + srow4, r2 = 8 + srow4, r3 = 12 + srow4;
    const ushort* Ag0 = Amat + (size_t)(bm + 16 * w + r0) * HD + ((ch ^ r0) << 3);
    const ushort* Ag1 = Amat + (size_t)(bm + 16 * w + r1) * HD + ((ch ^ r1) << 3);
    const ushort* Ag2 = Amat + (size_t)(bm + 16 * w + r2) * HD + ((ch ^ r2) << 3);
    const ushort* Ag3 = Amat + (size_t)(bm + 16 * w + r3) * HD + ((ch ^ r3) << 3);
    const ushort* Wg0 = W + (size_t)(16 * w + r0) * HD + ((ch ^ r0) << 3);
    const ushort* Wg1 = W + (size_t)(16 * w + r1) * HD + ((ch ^ r1) << 3);
    const ushort* Wg2 = W + (size_t)(16 * w + r2) * HD + ((ch ^ r2) << 3);
    const ushort* Wg3 = W + (size_t)(16 * w + r3) * HD + ((ch ^ r3) << 3);
    const int o0 = (16 * w +  0) * 128;
    const int o1 = (16 * w +  4) * 128;
    const int o2 = (16 * w +  8) * 128;
    const int o3 = (16 * w + 12) * 128;

    const int wm = (w >> 1) << 5;
    const int wn = (w & 1) << 5;
    const int fr = l & 15;
    const int fc = l >> 4;

    const int ra0 = wm + fr,  ra1 = wm + 16 + fr;
    const int rb0 = wn + fr,  rb1 = wn + 16 + fr;

    f32x4 acc00 = {0.f,0.f,0.f,0.f}, acc01 = {0.f,0.f,0.f,0.f};
    f32x4 acc10 = {0.f,0.f,0.f,0.f}, acc11 = {0.f,0.f,0.f,0.f};

    for (int kt = 0; kt < 8; ++kt) {
        const int ko = kt << 7;                // 128 elements per k-iter
        __syncthreads();                       // prev reads done before overwrite
        gld_lds16(Ag0 + ko, As + o0); gld_lds16(Wg0 + ko, Ws + o0);
        gld_lds16(Ag1 + ko, As + o1); gld_lds16(Wg1 + ko, Ws + o1);
        gld_lds16(Ag2 + ko, As + o2); gld_lds16(Wg2 + ko, Ws + o2);
        gld_lds16(Ag3 + ko, As + o3); gld_lds16(Wg3 + ko, Ws + o3);
        __syncthreads();                       // drains loads before reads
        #pragma unroll
        for (int kk = 0; kk < 4; ++kk) {
            const int c = (kk << 2) + fc;      // chunk 0..15
            bf16x8 a0 = *(const bf16x8*)(As + ra0 * 128 + ((c ^ (ra0 & 15)) << 3));
            bf16x8 a1 = *(const bf16x8*)(As + ra1 * 128 + ((c ^ (ra1 & 15)) << 3));
            bf16x8 b0 = *(const bf16x8*)(Ws + rb0 * 128 + ((c ^ (rb0 & 15)) << 3));
            bf16x8 b1 = *(const bf16x8*)(Ws + rb1 * 128 + ((c ^ (rb1 & 15)) << 3));
            acc00 = __builtin_amdgcn_mfma_f32_16x16x32_bf16(a0, b0, acc00, 0, 0, 0);
            acc01 = __builtin_amdgcn_mfma_f32_16x16x32_bf16(a0, b1, acc01, 0, 0, 0);
            acc10 = __builtin_amdgcn_mfma_f32_16x16x32_bf16(a1, b0, acc10, 0, 0, 0);
            acc11 = __builtin_amdgcn_mfma_f32_16x16x32_bf16(a1, b1, acc11, 0, 0, 0);
        }
    }

    const int bn = nt << 6;
    ushort* Cw = Cbuf + (size_t)(bm + wm) * NC + bn + wn;
    #pragma unroll
    for (int r = 0; r < 4; ++r) {
        const size_t ro0 = (size_t)(fc * 4 + r) * NC;
        const size_t ro1 = (size_t)(16 + fc * 4 + r) * NC;
        Cw[ro0 + fr]      = f2b(acc00[r]);
        Cw[ro0 + 16 + fr] = f2b(acc01[r]);
        Cw[ro1 + fr]      = f2b(acc10[r]);
        Cw[ro1 + 16 + fr] = f2b(acc11[r]);
    }
}

// ============================================================================
// gru1_first: step-0 GRU1 (out_prev = 0); writes h1,h1b and copies to h2,h2b.
// grid (512) x 1024 threads. Round-16 exact.
// ============================================================================
__global__ __launch_bounds__(1024) void gru1_first(
    const ushort* __restrict__ Cbuf, float* __restrict__ h1, ushort* __restrict__ h1b,
    float* __restrict__ h2, ushort* __restrict__ h2b,
    const float* __restrict__ note, const float* __restrict__ velc,
    const ushort* __restrict__ Wt1b, const float* __restrict__ b_ih1,
    const float* __restrict__ b_hh1)
{
    __shared__ float inp[22];
    const int b = blockIdx.x;
    const int j = threadIdx.x;

    if (j < 22) {
        float v = 0.f;
        if (j >= 9 && j < 18) v = note[(size_t)b * (SS * ND) + (j - 9)];
        else if (j >= 18)     v = velc[(size_t)b * (SS * VC) + (j - 18)];
        inp[j] = v;
    }
    __syncthreads();

    float ir = b_ih1[j], iz = b_ih1[HD + j], inn = b_ih1[2 * HD + j];
    #pragma unroll
    for (int c = 0; c < 22; ++c) {
        const float x = inp[c];
        const ushort* wr = Wt1b + c * N3;
        ir  = fmaf(x, b2f(wr[j]),          ir);
        iz  = fmaf(x, b2f(wr[HD + j]),     iz);
        inn = fmaf(x, b2f(wr[2 * HD + j]), inn);
    }

    const ushort* g = Cbuf + (size_t)b * NC + N3;     // gh1 section
    const float hr = b2f(g[j])          + b_hh1[j];
    const float hz = b2f(g[HD + j])     + b_hh1[HD + j];
    const float hn = b2f(g[2 * HD + j]) + b_hh1[2 * HD + j];

    const float rg = sigf(ir + hr);
    const float zg = sigf(iz + hz);
    const float n  = tanhf(inn + rg * hn);
    const float hnew = (1.f - zg) * n + zg * h1[(size_t)b * HD + j];
    const ushort hb = f2b(hnew);
    h1[(size_t)b * HD + j]  = hnew;
    h1b[(size_t)b * HD + j] = hb;
    h2[(size_t)b * HD + j]  = hnew;
    h2b[(size_t)b * HD + j] = hb;
}

// ============================================================================
// pw_fused(step): per block TWO batch rows (grid 256 x 1024 thr).
// Thread j owns row r = j>>9, cols c2 = 2*(j&511), +1 (ushort2/float2 loads).
// Round-18 exact.
// ============================================================================
__global__ __launch_bounds__(1024) void pw_fused(
    const ushort* __restrict__ Cbuf, float* __restrict__ h1, ushort* __restrict__ h1b,
    float* __restrict__ h2, ushort* __restrict__ h2b,
    const float* __restrict__ note, const float* __restrict__ velc,
    const ushort* __restrict__ Wt1b,
    const float* __restrict__ b_ih1, const float* __restrict__ b_hh1,
    const float* __restrict__ b_ih2, const float* __restrict__ b_hh2,
    const float* __restrict__ W_out, const float* __restrict__ b_out,
    float* __restrict__ dout, int step)
{
    __shared__ float hs[2][HD];
    __shared__ float inp[2][22];
    const int j  = threadIdx.x;
    const int b0 = blockIdx.x * 2;
    const int r  = j >> 9;              // row within pair
    const int c2 = (j & 511) << 1;      // first of two columns
    const int b  = b0 + r;

    // stage next-step note/velc for both rows
    if (step + 1 < SS && j < 64) {
        const int rr = j >> 5, c = j & 31;
        const int bb = b0 + rr;
        if (c >= 9 && c < 22)
            inp[rr][c] = (c < 18) ? note[(size_t)bb * (SS * ND) + (step + 1) * ND + (c - 9)]
                                  : velc[(size_t)bb * (SS * VC) + (step + 1) * VC + (c - 18)];
    }

    // ---- GRU2 (2 columns of row b) ----
    {
        const ushort* gi = Cbuf + (size_t)b * NC;          // gi2
        const ushort* gh = gi + 2 * N3;                    // gh2
        ushort2 gir = *(const ushort2*)(gi + c2);
        ushort2 giz = *(const ushort2*)(gi + HD + c2);
        ushort2 gin = *(const ushort2*)(gi + 2 * HD + c2);
        ushort2 ghr = *(const ushort2*)(gh + c2);
        ushort2 ghz = *(const ushort2*)(gh + HD + c2);
        ushort2 ghn = *(const ushort2*)(gh + 2 * HD + c2);
        float2 bir = *(const float2*)(b_ih2 + c2);
        float2 biz = *(const float2*)(b_ih2 + HD + c2);
        float2 bin = *(const float2*)(b_ih2 + 2 * HD + c2);
        float2 bhr = *(const float2*)(b_hh2 + c2);
        float2 bhz = *(const float2*)(b_hh2 + HD + c2);
        float2 bhn = *(const float2*)(b_hh2 + 2 * HD + c2);
        float2 h2v = *(const float2*)(h2 + (size_t)b * HD + c2);

        const float rg0 = sigf(b2f(gir.x) + bir.x + b2f(ghr.x) + bhr.x);
        const float zg0 = sigf(b2f(giz.x) + biz.x + b2f(ghz.x) + bhz.x);
        const float n0  = tanhf(b2f(gin.x) + bin.x + rg0 * (b2f(ghn.x) + bhn.x));
        const float hv0 = (1.f - zg0) * n0 + zg0 * h2v.x;
        const float rg1 = sigf(b2f(gir.y) + bir.y + b2f(ghr.y) + bhr.y);
        const float zg1 = sigf(b2f(giz.y) + biz.y + b2f(ghz.y) + bhz.y);
        const float n1  = tanhf(b2f(gin.y) + bin.y + rg1 * (b2f(ghn.y) + bhn.y));
        const float hv1 = (1.f - zg1) * n1 + zg1 * h2v.y;

        float2 hv = make_float2(hv0, hv1);
        *(float2*)(h2 + (size_t)b * HD + c2) = hv;
        ushort2 hb; hb.x = f2b(hv0); hb.y = f2b(hv1);
        *(ushort2*)(h2b + (size_t)b * HD + c2) = hb;
        hs[r][c2]     = hv0;
        hs[r][c2 + 1] = hv1;
    }
    __syncthreads();

    // out[b, step, :] — wave w: row rr = w&1, dots d = (w>>1) and (w>>1)+8
    const int w = j >> 6, t = j & 63;
    {
        const int rr = w & 1, bb = b0 + rr;
        #pragma unroll
        for (int dd = 0; dd < 2; ++dd) {
            const int d = (w >> 1) + dd * 8;
            if (d < ND) {
                float a = 0.f;
                const float* wr = W_out + (size_t)d * HD;
                #pragma unroll
                for (int k = 0; k < HD / 64; ++k)
                    a = fmaf(hs[rr][t + k * 64], wr[t + k * 64], a);
                #pragma unroll
                for (int off = 32; off > 0; off >>= 1) a += __shfl_down(a, off);
                if (t == 0) {
                    const float o = sigf(a + b_out[d]);
                    dout[(size_t)bb * (SS * ND) + step * ND + d] = o;
                    inp[rr][d] = o;
                }
            }
        }
    }
    __syncthreads();

    // ---- GRU1 for step+1 (2 columns of row b) ----
    if (step + 1 < SS) {
        float2 c1r = *(const float2*)(b_ih1 + c2);
        float2 c1z = *(const float2*)(b_ih1 + HD + c2);
        float2 c1n = *(const float2*)(b_ih1 + 2 * HD + c2);
        float xir0 = c1r.x, xir1 = c1r.y;
        float xiz0 = c1z.x, xiz1 = c1z.y;
        float xin0 = c1n.x, xin1 = c1n.y;
        #pragma unroll
        for (int c = 0; c < 22; ++c) {
            const float x = inp[r][c];
            ushort2 w0 = *(const ushort2*)(Wt1b + c * N3 + c2);
            ushort2 w1 = *(const ushort2*)(Wt1b + c * N3 + HD + c2);
            ushort2 w2 = *(const ushort2*)(Wt1b + c * N3 + 2 * HD + c2);
            xir0 = fmaf(x, b2f(w0.x), xir0); xir1 = fmaf(x, b2f(w0.y), xir1);
            xiz0 = fmaf(x, b2f(w1.x), xiz0); xiz1 = fmaf(x, b2f(w1.y), xiz1);
            xin0 = fmaf(x, b2f(w2.x), xin0); xin1 = fmaf(x, b2f(w2.y), xin1);
        }
        const ushort* g1 = Cbuf + (size_t)b * NC + N3;  // gh1 (for step+1)
        ushort2 g1r = *(const ushort2*)(g1 + c2);
        ushort2 g1z = *(const ushort2*)(g1 + HD + c2);
        ushort2 g1n = *(const ushort2*)(g1 + 2 * HD + c2);
        float2 d1r = *(const float2*)(b_hh1 + c2);
        float2 d1z = *(const float2*)(b_hh1 + HD + c2);
        float2 d1n = *(const float2*)(b_hh1 + 2 * HD + c2);
        float2 h1v = *(const float2*)(h1 + (size_t)b * HD + c2);

        const float rg0 = sigf(xir0 + b2f(g1r.x) + d1r.x);
        const float zg0 = sigf(xiz0 + b2f(g1z.x) + d1z.x);
        const float n0  = tanhf(xin0 + rg0 * (b2f(g1n.x) + d1n.x));
        const float hv0 = (1.f - zg0) * n0 + zg0 * h1v.x;
        const float rg1 = sigf(xir1 + b2f(g1r.y) + d1r.y);
        const float zg1 = sigf(xiz1 + b2f(g1z.y) + d1z.y);
        const float n1  = tanhf(xin1 + rg1 * (b2f(g1n.y) + d1n.y));
        const float hv1 = (1.f - zg1) * n1 + zg1 * h1v.y;

        float2 hv = make_float2(hv0, hv1);
        *(float2*)(h1 + (size_t)b * HD + c2) = hv;
        ushort2 hb; hb.x = f2b(hv0); hb.y = f2b(hv1);
        *(ushort2*)(h1b + (size_t)b * HD + c2) = hb;
    }
}

// ============================================================================
extern "C" void kernel_launch(void* const* d_in, const int* in_sizes, int n_in,
                              void* d_out, int out_size, void* d_ws, size_t ws_size,
                              hipStream_t stream)
{
    const float* z     = (const float*)d_in[0];
    const float* ne    = (const float*)d_in[1];
    const float* note  = (const float*)d_in[3];
    const float* velc  = (const float*)d_in[4];
    const float* gc    = (const float*)d_in[5];
    const float* W_in  = (const float*)d_in[6];
    const float* b_in  = (const float*)d_in[7];
    const float* W_ih1 = (const float*)d_in[8];
    const float* W_hh1 = (const float*)d_in[9];
    const float* b_ih1 = (const float*)d_in[10];
    const float* b_hh1 = (const float*)d_in[11];
    const float* W_ih2 = (const float*)d_in[12];
    const float* W_hh2 = (const float*)d_in[13];
    const float* b_ih2 = (const float*)d_in[14];
    const float* b_hh2 = (const float*)d_in[15];
    const float* W_out = (const float*)d_in[16];
    const float* b_out = (const float*)d_in[17];
    float* out = (float*)d_out;

    // workspace layout (~34 MB)
    float*  h1   = (float*)d_ws;                     // [512*1024] f32
    float*  h2   = h1 + BB * HD;                     // [512*1024] f32
    ushort* Wt1b = (ushort*)(h2 + BB * HD);          // [22*3072]  bf16
    ushort* Cbuf = Wt1b + 22 * N3;                   // [512*9216] bf16
    ushort* h1b  = Cbuf + (size_t)BB * NC;           // [512*1024] bf16
    ushort* h2b  = h1b + BB * HD;                    // [512*1024] bf16
    ushort* Wcat = h2b + BB * HD;                    // [9216*1024] bf16
    // init-only buffers aliased into Cbuf (consumed before Cbuf is written)
    ushort* Acat  = Cbuf;                            // [512*832]
    ushort* W_inb = Acat + (size_t)BB * KI;          // [1024*832]

    prep_w   <<<dim3(NC), 256, 0, stream>>>(W_ih2, W_hh1, W_hh2, Wcat);
    prep_wt1 <<<dim3(12), 256, 0, stream>>>(W_ih1, Wt1b);
    prep_acat<<<dim3(BB), 256, 0, stream>>>(z, ne, gc, Acat);
    prep_win <<<dim3(HD), 256, 0, stream>>>(W_in, W_inb);

    k_init<<<dim3(128), 256, 0, stream>>>(Acat, W_inb, b_in, h1, h1b);

    // prologue: gh1(0)  (n-tiles 48..95)
    gemm3<<<dim3(8, 48), 256, 0, stream>>>(h1b, h2b, Wcat, Cbuf, 48, 0);
    gru1_first<<<dim3(BB), 1024, 0, stream>>>(Cbuf, h1, h1b, h2, h2b,
                                              note, velc, Wt1b, b_ih1, b_hh1);

    for (int s = 0; s < SS; ++s) {
        // gi2(s) | gh1(s+1) | gh2(s); last step skips the unused gh1 section
        if (s + 1 < SS)
            gemm3<<<dim3(8, 144), 256, 0, stream>>>(h1b, h2b, Wcat, Cbuf, 0, 0);
        else
            gemm3<<<dim3(8, 96), 256, 0, stream>>>(h1b, h2b, Wcat, Cbuf, 0, 1);
        pw_fused<<<dim3(BB / 2), 1024, 0, stream>>>(Cbuf, h1, h1b, h2, h2b,
                                                    note, velc, Wt1b,
                                                    b_ih1, b_hh1, b_ih2, b_hh2,
                                                    W_out, b_out, out, s);
    }
}

// Round 20
// 1776.701 us; speedup vs baseline: 1.0717x; 1.0717x over previous
//
#include <hip/hip_runtime.h>
#include <hip/hip_bf16.h>

#define HD 1024
#define BB 512
#define SS 64
#define N3 3072
#define NC 9216      // Cbuf cols (bf16): gi2 | gh1 | gh2
#define ND 9
#define VC 4
#define KI 832       // padded K for init GEMM (784 -> 13*64)

typedef __attribute__((ext_vector_type(8))) short bf16x8;
typedef __attribute__((ext_vector_type(4))) float f32x4;

__device__ __forceinline__ ushort f2b(float f) {
    unsigned u = __builtin_bit_cast(unsigned, f);
    u += 0x7fffu + ((u >> 16) & 1u);          // round-to-nearest-even
    return (ushort)(u >> 16);
}

__device__ __forceinline__ float b2f(ushort u) {
    unsigned x = ((unsigned)u) << 16;
    return __builtin_bit_cast(float, x);
}

__device__ __forceinline__ float sigf(float x) {
    return 1.f / (1.f + __expf(-x));
}

__device__ __forceinline__ void gld_lds16(const void* g, void* l) {
    __builtin_amdgcn_global_load_lds(
        (const __attribute__((address_space(1))) unsigned int*)g,
        (__attribute__((address_space(3))) unsigned int*)l, 16, 0, 0);
}

// ============================================================================
// prep kernels
// ============================================================================
__global__ __launch_bounds__(256) void prep_w(
    const float* __restrict__ Wih2, const float* __restrict__ Whh1,
    const float* __restrict__ Whh2, ushort* __restrict__ Wcat)
{
    const int row = blockIdx.x;
    const float* src = row < 3072 ? Wih2 + (size_t)row * HD
                     : row < 6144 ? Whh1 + (size_t)(row - 3072) * HD
                                  : Whh2 + (size_t)(row - 6144) * HD;
    const int c = threadIdx.x * 4;
    float4 v = *(const float4*)(src + c);
    ushort4 o;
    o.x = f2b(v.x); o.y = f2b(v.y); o.z = f2b(v.z); o.w = f2b(v.w);
    *(ushort4*)(Wcat + (size_t)row * HD + c) = o;
}

__global__ __launch_bounds__(256) void prep_wt1(
    const float* __restrict__ Wih1, ushort* __restrict__ Wt1b)
{
    const int g = blockIdx.x * 256 + threadIdx.x;
    #pragma unroll
    for (int c = 0; c < 22; ++c)
        Wt1b[c * N3 + g] = f2b(Wih1[(size_t)g * 22 + c]);
}

__global__ __launch_bounds__(256) void prep_acat(
    const float* __restrict__ z, const float* __restrict__ ne,
    const float* __restrict__ gc, ushort* __restrict__ Acat)
{
    const int b = blockIdx.x;
    const int t = threadIdx.x;
    if (t >= 208) return;
    const int c = t * 4;
    float4 v = make_float4(0.f, 0.f, 0.f, 0.f);
    if (c < 256)      v = *(const float4*)(z  + (size_t)b * 256 + c);
    else if (c < 768) v = *(const float4*)(ne + (size_t)b * 512 + (c - 256));
    else if (c < 784) v = *(const float4*)(gc + (size_t)b * 16  + (c - 768));
    ushort4 o;
    o.x = f2b(v.x); o.y = f2b(v.y); o.z = f2b(v.z); o.w = f2b(v.w);
    *(ushort4*)(Acat + (size_t)b * KI + c) = o;
}

__global__ __launch_bounds__(256) void prep_win(
    const float* __restrict__ W_in, ushort* __restrict__ W_inb)
{
    const int r = blockIdx.x;
    const int t = threadIdx.x;
    if (t >= 208) return;
    const int c = t * 4;
    ushort4 o = {0, 0, 0, 0};
    if (c < 784) {
        float4 v = *(const float4*)(W_in + (size_t)r * 784 + c);
        o.x = f2b(v.x); o.y = f2b(v.y); o.z = f2b(v.z); o.w = f2b(v.w);
    }
    *(ushort4*)(W_inb + (size_t)r * KI + c) = o;
}

// ============================================================================
// k_init: h1 = tanh(Acat @ W_inb^T + b_in). BK=64 dbuf (verified R9-R18).
// ============================================================================
__global__ __launch_bounds__(256) void k_init(
    const ushort* __restrict__ Acat, const ushort* __restrict__ W_inb,
    const float* __restrict__ b_in, float* __restrict__ h1, ushort* __restrict__ h1b)
{
    __shared__ __align__(16) ushort As[2 * 4096];
    __shared__ __align__(16) ushort Bs[2 * 4096];
    const int t = blockIdx.x;
    const int nt = t >> 3, mt = t & 7;

    const int tid = threadIdx.x;
    const int w = tid >> 6, l = tid & 63;
    const int lr = l >> 3;
    const int sw = ((l & 7) ^ lr) << 3;

    const ushort* Ag0 = Acat + ((size_t)(mt << 6) + 16 * w + lr) * KI + sw;
    const ushort* Ag1 = Ag0 + 8 * KI;
    const ushort* Bg0 = W_inb + ((size_t)(nt << 6) + 16 * w + lr) * KI + sw;
    const ushort* Bg1 = Bg0 + 8 * KI;
    const int o0 = (16 * w) * 64, o1 = (16 * w + 8) * 64;

    gld_lds16(Ag0, As + o0); gld_lds16(Ag1, As + o1);
    gld_lds16(Bg0, Bs + o0); gld_lds16(Bg1, Bs + o1);

    const int wm = (w >> 1) << 5, wn = (w & 1) << 5;
    const int fr = l & 15, fc = l >> 4;
    const int ra0 = wm + fr, ra1 = wm + 16 + fr;
    const int rb0 = wn + fr, rb1 = wn + 16 + fr;

    f32x4 acc[2][2] = {};
    for (int kt = 0; kt < 13; ++kt) {
        const int cb = (kt & 1) << 12;
        __syncthreads();
        if (kt + 1 < 13) {
            const int nb = ((kt + 1) & 1) << 12;
            const int ko = (kt + 1) << 6;
            gld_lds16(Ag0 + ko, As + nb + o0);
            gld_lds16(Ag1 + ko, As + nb + o1);
            gld_lds16(Bg0 + ko, Bs + nb + o0);
            gld_lds16(Bg1 + ko, Bs + nb + o1);
        }
        #pragma unroll
        for (int kk = 0; kk < 2; ++kk) {
            const int c = (kk << 2) + fc;
            bf16x8 a0 = *(const bf16x8*)(As + cb + ra0 * 64 + ((c ^ (ra0 & 7)) << 3));
            bf16x8 a1 = *(const bf16x8*)(As + cb + ra1 * 64 + ((c ^ (ra1 & 7)) << 3));
            bf16x8 b0 = *(const bf16x8*)(Bs + cb + rb0 * 64 + ((c ^ (rb0 & 7)) << 3));
            bf16x8 b1 = *(const bf16x8*)(Bs + cb + rb1 * 64 + ((c ^ (rb1 & 7)) << 3));
            acc[0][0] = __builtin_amdgcn_mfma_f32_16x16x32_bf16(a0, b0, acc[0][0], 0, 0, 0);
            acc[0][1] = __builtin_amdgcn_mfma_f32_16x16x32_bf16(a0, b1, acc[0][1], 0, 0, 0);
            acc[1][0] = __builtin_amdgcn_mfma_f32_16x16x32_bf16(a1, b0, acc[1][0], 0, 0, 0);
            acc[1][1] = __builtin_amdgcn_mfma_f32_16x16x32_bf16(a1, b1, acc[1][1], 0, 0, 0);
        }
    }

    const int row0 = (mt << 6) + wm;
    const int col0 = (nt << 6) + wn + fr;
    const float b0v = b_in[col0], b1v = b_in[col0 + 16];
    #pragma unroll
    for (int i = 0; i < 2; ++i) {
        #pragma unroll
        for (int r = 0; r < 4; ++r) {
            const int row = row0 + i * 16 + fc * 4 + r;
            const float v0 = tanhf(acc[i][0][r] + b0v);
            const float v1 = tanhf(acc[i][1][r] + b1v);
            h1[(size_t)row * HD + col0]       = v0;
            h1b[(size_t)row * HD + col0]      = f2b(v0);
            h1[(size_t)row * HD + col0 + 16]  = v1;
            h1b[(size_t)row * HD + col0 + 16] = f2b(v1);
        }
    }
}

// ============================================================================
// gemm3: Cbuf(bf16)[512, 9216] = [h1b@Wih2^T | h1b@Whh1^T | h2b@Whh2^T]
// SETTLED structure (8 challengers falsified): 64x64 tile, BK=64,
// single-buffered 16KB LDS, 2 barriers/k-iter, global_load_lds w16,
// XOR swizzle, XCD-chunked block swizzle, bf16 C-write.
// ============================================================================
__global__ __launch_bounds__(256) void gemm3(
    const ushort* __restrict__ h1b, const ushort* __restrict__ h2b,
    const ushort* __restrict__ Wcat, ushort* __restrict__ Cbuf, int ntb, int skip48)
{
    __shared__ __align__(16) ushort As[4096];   // [64][64] linear
    __shared__ __align__(16) ushort Ws[4096];

    const int flat = blockIdx.x + (blockIdx.y << 3);
    const int id   = (flat & 7) * gridDim.y + (flat >> 3);
    const int bm   = (id & 7) << 6;
    int nt         = (id >> 3) + ntb;          // global n-tile
    if (skip48 && nt >= 48) nt += 48;          // skip gh1 section

    const ushort* Amat = (nt < 96) ? h1b : h2b;
    const ushort* W    = Wcat + (size_t)(nt << 6) * HD;

    const int tid = threadIdx.x;
    const int w   = tid >> 6;
    const int l   = tid & 63;

    const int srow = l >> 3;
    const int sch  = ((l & 7) ^ srow) << 3;
    const ushort* Ag0 = Amat + (size_t)(bm + 16 * w + srow) * HD + sch;
    const ushort* Ag1 = Ag0 + 8 * HD;
    const ushort* Wg0 = W + (size_t)(16 * w + srow) * HD + sch;
    const ushort* Wg1 = Wg0 + 8 * HD;
    ushort* Al0 = As + (16 * w) * 64;
    ushort* Al1 = As + (16 * w + 8) * 64;
    ushort* Wl0 = Ws + (16 * w) * 64;
    ushort* Wl1 = Ws + (16 * w + 8) * 64;

    const int wm = (w >> 1) << 5;
    const int wn = (w & 1) << 5;
    const int fr = l & 15;
    const int fc = l >> 4;

    const int ra0 = wm + fr,  ra1 = wm + 16 + fr;
    const int rb0 = wn + fr,  rb1 = wn + 16 + fr;

    f32x4 acc00 = {0.f,0.f,0.f,0.f}, acc01 = {0.f,0.f,0.f,0.f};
    f32x4 acc10 = {0.f,0.f,0.f,0.f}, acc11 = {0.f,0.f,0.f,0.f};

    for (int kt = 0; kt < 16; ++kt) {
        const int ko = kt << 6;
        __syncthreads();
        gld_lds16(Ag0 + ko, Al0);
        gld_lds16(Ag1 + ko, Al1);
        gld_lds16(Wg0 + ko, Wl0);
        gld_lds16(Wg1 + ko, Wl1);
        __syncthreads();
        #pragma unroll
        for (int kk = 0; kk < 2; ++kk) {
            const int c = (kk << 2) + fc;
            bf16x8 a0 = *(const bf16x8*)(As + ra0 * 64 + ((c ^ (ra0 & 7)) << 3));
            bf16x8 a1 = *(const bf16x8*)(As + ra1 * 64 + ((c ^ (ra1 & 7)) << 3));
            bf16x8 b0 = *(const bf16x8*)(Ws + rb0 * 64 + ((c ^ (rb0 & 7)) << 3));
            bf16x8 b1 = *(const bf16x8*)(Ws + rb1 * 64 + ((c ^ (rb1 & 7)) << 3));
            acc00 = __builtin_amdgcn_mfma_f32_16x16x32_bf16(a0, b0, acc00, 0, 0, 0);
            acc01 = __builtin_amdgcn_mfma_f32_16x16x32_bf16(a0, b1, acc01, 0, 0, 0);
            acc10 = __builtin_amdgcn_mfma_f32_16x16x32_bf16(a1, b0, acc10, 0, 0, 0);
            acc11 = __builtin_amdgcn_mfma_f32_16x16x32_bf16(a1, b1, acc11, 0, 0, 0);
        }
    }

    const int bn = nt << 6;
    ushort* Cw = Cbuf + (size_t)(bm + wm) * NC + bn + wn;
    #pragma unroll
    for (int r = 0; r < 4; ++r) {
        const size_t ro0 = (size_t)(fc * 4 + r) * NC;
        const size_t ro1 = (size_t)(16 + fc * 4 + r) * NC;
        Cw[ro0 + fr]      = f2b(acc00[r]);
        Cw[ro0 + 16 + fr] = f2b(acc01[r]);
        Cw[ro1 + fr]      = f2b(acc10[r]);
        Cw[ro1 + 16 + fr] = f2b(acc11[r]);
    }
}

// ============================================================================
// gru1_first: step-0 GRU1 (out_prev = 0); writes h1,h1b and copies to h2,h2b.
// grid (512) x 1024 threads.
// ============================================================================
__global__ __launch_bounds__(1024) void gru1_first(
    const ushort* __restrict__ Cbuf, float* __restrict__ h1, ushort* __restrict__ h1b,
    float* __restrict__ h2, ushort* __restrict__ h2b,
    const float* __restrict__ note, const float* __restrict__ velc,
    const ushort* __restrict__ Wt1b, const float* __restrict__ b_ih1,
    const float* __restrict__ b_hh1)
{
    __shared__ float inp[22];
    const int b = blockIdx.x;
    const int j = threadIdx.x;

    if (j < 22) {
        float v = 0.f;
        if (j >= 9 && j < 18) v = note[(size_t)b * (SS * ND) + (j - 9)];
        else if (j >= 18)     v = velc[(size_t)b * (SS * VC) + (j - 18)];
        inp[j] = v;
    }
    __syncthreads();

    float ir = b_ih1[j], iz = b_ih1[HD + j], inn = b_ih1[2 * HD + j];
    #pragma unroll
    for (int c = 0; c < 22; ++c) {
        const float x = inp[c];
        const ushort* wr = Wt1b + c * N3;
        ir  = fmaf(x, b2f(wr[j]),          ir);
        iz  = fmaf(x, b2f(wr[HD + j]),     iz);
        inn = fmaf(x, b2f(wr[2 * HD + j]), inn);
    }

    const ushort* g = Cbuf + (size_t)b * NC + N3;     // gh1 section
    const float hr = b2f(g[j])          + b_hh1[j];
    const float hz = b2f(g[HD + j])     + b_hh1[HD + j];
    const float hn = b2f(g[2 * HD + j]) + b_hh1[2 * HD + j];

    const float rg = sigf(ir + hr);
    const float zg = sigf(iz + hz);
    const float n  = tanhf(inn + rg * hn);
    const float hnew = (1.f - zg) * n + zg * h1[(size_t)b * HD + j];
    const ushort hb = f2b(hnew);
    h1[(size_t)b * HD + j]  = hnew;
    h1b[(size_t)b * HD + j] = hb;
    h2[(size_t)b * HD + j]  = hnew;
    h2b[(size_t)b * HD + j] = hb;
}

// ============================================================================
// pw_fused(step): per block TWO batch rows (grid 256 x 1024 thr).
// Thread j owns row r = j>>9, cols c2 = 2*(j&511), +1 (ushort2/float2 loads).
// ============================================================================
__global__ __launch_bounds__(1024) void pw_fused(
    const ushort* __restrict__ Cbuf, float* __restrict__ h1, ushort* __restrict__ h1b,
    float* __restrict__ h2, ushort* __restrict__ h2b,
    const float* __restrict__ note, const float* __restrict__ velc,
    const ushort* __restrict__ Wt1b,
    const float* __restrict__ b_ih1, const float* __restrict__ b_hh1,
    const float* __restrict__ b_ih2, const float* __restrict__ b_hh2,
    const float* __restrict__ W_out, const float* __restrict__ b_out,
    float* __restrict__ dout, int step)
{
    __shared__ float hs[2][HD];
    __shared__ float inp[2][22];
    const int j  = threadIdx.x;
    const int b0 = blockIdx.x * 2;
    const int r  = j >> 9;              // row within pair
    const int c2 = (j & 511) << 1;      // first of two columns
    const int b  = b0 + r;

    // stage next-step note/velc for both rows
    if (step + 1 < SS && j < 64) {
        const int rr = j >> 5, c = j & 31;
        const int bb = b0 + rr;
        if (c >= 9 && c < 22)
            inp[rr][c] = (c < 18) ? note[(size_t)bb * (SS * ND) + (step + 1) * ND + (c - 9)]
                                  : velc[(size_t)bb * (SS * VC) + (step + 1) * VC + (c - 18)];
    }

    // ---- GRU2 (2 columns of row b) ----
    {
        const ushort* gi = Cbuf + (size_t)b * NC;          // gi2
        const ushort* gh = gi + 2 * N3;                    // gh2
        ushort2 gir = *(const ushort2*)(gi + c2);
        ushort2 giz = *(const ushort2*)(gi + HD + c2);
        ushort2 gin = *(const ushort2*)(gi + 2 * HD + c2);
        ushort2 ghr = *(const ushort2*)(gh + c2);
        ushort2 ghz = *(const ushort2*)(gh + HD + c2);
        ushort2 ghn = *(const ushort2*)(gh + 2 * HD + c2);
        float2 bir = *(const float2*)(b_ih2 + c2);
        float2 biz = *(const float2*)(b_ih2 + HD + c2);
        float2 bin = *(const float2*)(b_ih2 + 2 * HD + c2);
        float2 bhr = *(const float2*)(b_hh2 + c2);
        float2 bhz = *(const float2*)(b_hh2 + HD + c2);
        float2 bhn = *(const float2*)(b_hh2 + 2 * HD + c2);
        float2 h2v = *(const float2*)(h2 + (size_t)b * HD + c2);

        const float rg0 = sigf(b2f(gir.x) + bir.x + b2f(ghr.x) + bhr.x);
        const float zg0 = sigf(b2f(giz.x) + biz.x + b2f(ghz.x) + bhz.x);
        const float n0  = tanhf(b2f(gin.x) + bin.x + rg0 * (b2f(ghn.x) + bhn.x));
        const float hv0 = (1.f - zg0) * n0 + zg0 * h2v.x;
        const float rg1 = sigf(b2f(gir.y) + bir.y + b2f(ghr.y) + bhr.y);
        const float zg1 = sigf(b2f(giz.y) + biz.y + b2f(ghz.y) + bhz.y);
        const float n1  = tanhf(b2f(gin.y) + bin.y + rg1 * (b2f(ghn.y) + bhn.y));
        const float hv1 = (1.f - zg1) * n1 + zg1 * h2v.y;

        float2 hv = make_float2(hv0, hv1);
        *(float2*)(h2 + (size_t)b * HD + c2) = hv;
        ushort2 hb; hb.x = f2b(hv0); hb.y = f2b(hv1);
        *(ushort2*)(h2b + (size_t)b * HD + c2) = hb;
        hs[r][c2]     = hv0;
        hs[r][c2 + 1] = hv1;
    }
    __syncthreads();

    // out[b, step, :] — wave w: row rr = w&1, dots d = (w>>1) and (w>>1)+8
    const int w = j >> 6, t = j & 63;
    {
        const int rr = w & 1, bb = b0 + rr;
        #pragma unroll
        for (int dd = 0; dd < 2; ++dd) {
            const int d = (w >> 1) + dd * 8;
            if (d < ND) {
                float a = 0.f;
                const float* wr = W_out + (size_t)d * HD;
                #pragma unroll
                for (int k = 0; k < HD / 64; ++k)
                    a = fmaf(hs[rr][t + k * 64], wr[t + k * 64], a);
                #pragma unroll
                for (int off = 32; off > 0; off >>= 1) a += __shfl_down(a, off);
                if (t == 0) {
                    const float o = sigf(a + b_out[d]);
                    dout[(size_t)bb * (SS * ND) + step * ND + d] = o;
                    inp[rr][d] = o;
                }
            }
        }
    }
    __syncthreads();

    // ---- GRU1 for step+1 (2 columns of row b) ----
    if (step + 1 < SS) {
        float2 c1r = *(const float2*)(b_ih1 + c2);
        float2 c1z = *(const float2*)(b_ih1 + HD + c2);
        float2 c1n = *(const float2*)(b_ih1 + 2 * HD + c2);
        float xir0 = c1r.x, xir1 = c1r.y;
        float xiz0 = c1z.x, xiz1 = c1z.y;
        float xin0 = c1n.x, xin1 = c1n.y;
        #pragma unroll
        for (int c = 0; c < 22; ++c) {
            const float x = inp[r][c];
            ushort2 w0 = *(const ushort2*)(Wt1b + c * N3 + c2);
            ushort2 w1 = *(const ushort2*)(Wt1b + c * N3 + HD + c2);
            ushort2 w2 = *(const ushort2*)(Wt1b + c * N3 + 2 * HD + c2);
            xir0 = fmaf(x, b2f(w0.x), xir0); xir1 = fmaf(x, b2f(w0.y), xir1);
            xiz0 = fmaf(x, b2f(w1.x), xiz0); xiz1 = fmaf(x, b2f(w1.y), xiz1);
            xin0 = fmaf(x, b2f(w2.x), xin0); xin1 = fmaf(x, b2f(w2.y), xin1);
        }
        const ushort* g1 = Cbuf + (size_t)b * NC + N3;  // gh1 (for step+1)
        ushort2 g1r = *(const ushort2*)(g1 + c2);
        ushort2 g1z = *(const ushort2*)(g1 + HD + c2);
        ushort2 g1n = *(const ushort2*)(g1 + 2 * HD + c2);
        float2 d1r = *(const float2*)(b_hh1 + c2);
        float2 d1z = *(const float2*)(b_hh1 + HD + c2);
        float2 d1n = *(const float2*)(b_hh1 + 2 * HD + c2);
        float2 h1v = *(const float2*)(h1 + (size_t)b * HD + c2);

        const float rg0 = sigf(xir0 + b2f(g1r.x) + d1r.x);
        const float zg0 = sigf(xiz0 + b2f(g1z.x) + d1z.x);
        const float n0  = tanhf(xin0 + rg0 * (b2f(g1n.x) + d1n.x));
        const float hv0 = (1.f - zg0) * n0 + zg0 * h1v.x;
        const float rg1 = sigf(xir1 + b2f(g1r.y) + d1r.y);
        const float zg1 = sigf(xiz1 + b2f(g1z.y) + d1z.y);
        const float n1  = tanhf(xin1 + rg1 * (b2f(g1n.y) + d1n.y));
        const float hv1 = (1.f - zg1) * n1 + zg1 * h1v.y;

        float2 hv = make_float2(hv0, hv1);
        *(float2*)(h1 + (size_t)b * HD + c2) = hv;
        ushort2 hb; hb.x = f2b(hv0); hb.y = f2b(hv1);
        *(ushort2*)(h1b + (size_t)b * HD + c2) = hb;
    }
}

// ============================================================================
extern "C" void kernel_launch(void* const* d_in, const int* in_sizes, int n_in,
                              void* d_out, int out_size, void* d_ws, size_t ws_size,
                              hipStream_t stream)
{
    const float* z     = (const float*)d_in[0];
    const float* ne    = (const float*)d_in[1];
    const float* note  = (const float*)d_in[3];
    const float* velc  = (const float*)d_in[4];
    const float* gc    = (const float*)d_in[5];
    const float* W_in  = (const float*)d_in[6];
    const float* b_in  = (const float*)d_in[7];
    const float* W_ih1 = (const float*)d_in[8];
    const float* W_hh1 = (const float*)d_in[9];
    const float* b_ih1 = (const float*)d_in[10];
    const float* b_hh1 = (const float*)d_in[11];
    const float* W_ih2 = (const float*)d_in[12];
    const float* W_hh2 = (const float*)d_in[13];
    const float* b_ih2 = (const float*)d_in[14];
    const float* b_hh2 = (const float*)d_in[15];
    const float* W_out = (const float*)d_in[16];
    const float* b_out = (const float*)d_in[17];
    float* out = (float*)d_out;

    // workspace layout (~34 MB)
    float*  h1   = (float*)d_ws;                     // [512*1024] f32
    float*  h2   = h1 + BB * HD;                     // [512*1024] f32
    ushort* Wt1b = (ushort*)(h2 + BB * HD);          // [22*3072]  bf16
    ushort* Cbuf = Wt1b + 22 * N3;                   // [512*9216] bf16
    ushort* h1b  = Cbuf + (size_t)BB * NC;           // [512*1024] bf16
    ushort* h2b  = h1b + BB * HD;                    // [512*1024] bf16
    ushort* Wcat = h2b + BB * HD;                    // [9216*1024] bf16
    // init-only buffers aliased into Cbuf (consumed before Cbuf is written)
    ushort* Acat  = Cbuf;                            // [512*832]
    ushort* W_inb = Acat + (size_t)BB * KI;          // [1024*832]

    prep_w   <<<dim3(NC), 256, 0, stream>>>(W_ih2, W_hh1, W_hh2, Wcat);
    prep_wt1 <<<dim3(12), 256, 0, stream>>>(W_ih1, Wt1b);
    prep_acat<<<dim3(BB), 256, 0, stream>>>(z, ne, gc, Acat);
    prep_win <<<dim3(HD), 256, 0, stream>>>(W_in, W_inb);

    k_init<<<dim3(128), 256, 0, stream>>>(Acat, W_inb, b_in, h1, h1b);

    // prologue: gh1(0)  (n-tiles 48..95)
    gemm3<<<dim3(8, 48), 256, 0, stream>>>(h1b, h2b, Wcat, Cbuf, 48, 0);
    gru1_first<<<dim3(BB), 1024, 0, stream>>>(Cbuf, h1, h1b, h2, h2b,
                                              note, velc, Wt1b, b_ih1, b_hh1);

    for (int s = 0; s < SS; ++s) {
        // gi2(s) | gh1(s+1) | gh2(s); last step skips the unused gh1 section
        if (s + 1 < SS)
            gemm3<<<dim3(8, 144), 256, 0, stream>>>(h1b, h2b, Wcat, Cbuf, 0, 0);
        else
            gemm3<<<dim3(8, 96), 256, 0, stream>>>(h1b, h2b, Wcat, Cbuf, 0, 1);
        pw_fused<<<dim3(BB / 2), 1024, 0, stream>>>(Cbuf, h1, h1b, h2, h2b,
                                                    note, velc, Wt1b,
                                                    b_ih1, b_hh1, b_ih2, b_hh2,
                                                    W_out, b_out, out, s);
    }
}